// Round 4
// baseline (250.243 us; speedup 1.0000x reference)
//
#include <hip/hip_runtime.h>
#include <hip/hip_bf16.h>
#include <cstdint>

#define N_IDE 4096
#define M_U   16384
#define D_DIM 256
#define EPSF  1e-12f
#define INV_M (1.0f / 16384.0f)

typedef _Float16 f16x8 __attribute__((ext_vector_type(8)));
typedef float    f32x4 __attribute__((ext_vector_type(4)));

// ---- async global->LDS 16B copy. LDS dest = wave-uniform base + lane*16. ----
__device__ __forceinline__ void gll16(const void* g, void* l) {
  __builtin_amdgcn_global_load_lds(
      (const __attribute__((address_space(1))) void*)(uintptr_t)g,
      (__attribute__((address_space(3))) void*)(uint32_t)(uintptr_t)l,
      16, 0, 0);
}

__device__ __forceinline__ unsigned short f2h_bits(float f) {
  _Float16 h = (_Float16)f;
  return __builtin_bit_cast(unsigned short, h);
}

#define SBAR()  asm volatile("s_barrier" ::: "memory")

// ---- Kernel 1: fp32 -> f16 convert + row squared-norms (one wave per row) ----
__global__ __launch_bounds__(256) void k_conv(const float* __restrict__ ide,
                                              const float* __restrict__ u,
                                              unsigned short* __restrict__ Ah,
                                              unsigned short* __restrict__ Bh,
                                              float* __restrict__ x2,
                                              float* __restrict__ y2,
                                              float* __restrict__ out) {
  if (blockIdx.x == 0 && threadIdx.x == 0) out[0] = 0.f;   // replaces memset launch
  int gw = (blockIdx.x * 256 + threadIdx.x) >> 6;
  int l  = threadIdx.x & 63;
  const float4* src;
  ushort4* dst;
  float* nrm;
  if (gw < N_IDE) {
    src = (const float4*)(ide + (size_t)gw * D_DIM);
    dst = (ushort4*)(Ah + (size_t)gw * D_DIM);
    nrm = x2 + gw;
  } else {
    int r = gw - N_IDE;
    src = (const float4*)(u + (size_t)r * D_DIM);
    dst = (ushort4*)(Bh + (size_t)r * D_DIM);
    nrm = y2 + r;
  }
  float4 v = src[l];
  float s = v.x * v.x + v.y * v.y + v.z * v.z + v.w * v.w;
  ushort4 o;
  o.x = f2h_bits(v.x); o.y = f2h_bits(v.y);
  o.z = f2h_bits(v.z); o.w = f2h_bits(v.w);
  dst[l] = o;
#pragma unroll
  for (int m = 1; m <= 32; m <<= 1) s += __shfl_xor(s, m, 64);
  if (l == 0) *nrm = s;
}

// ---- Kernel 2: MFMA-first-window counted-vmcnt GEMM ----
// grid (64, 16), 512 threads = 8 waves (2M x 4N). Block tile 256x256, BK=64,
// K=256 -> 4 K-tiles, fully unrolled. Wave tile 128x64: acc[8][4] (128 AGPR).
// LDS: A dbuf 2x32KB + B dbuf 2x32KB (XOR-swizzled k-slots) + rowacc 4KB.
// WINDOW STRUCTURE (the r3 fix): each window runs the MFMA cluster FIRST
// (on fragments ds_read in the PREVIOUS window), then issues next window's
// ds_reads, then s_barrier. A wave's reads drain in the LDS pipe while it
// waits at the barrier / while other waves' MFMAs run -> LDS and MFMA pipes
// overlap instead of serializing (r0-r3 all had reads-then-MFMA windows:
// per-phase cost = LDSdrain + MFMAdrain, MfmaUtil pinned at ~24%).
// Staging: all 4 half-tiles of K-tile kt+1 issued in w0; vmcnt(0) at w2
// (~1400 cyc later, L2-resident source -> effectively free); w2's barrier is
// the publish point; w3 reads the next K-tile's first fragments after it.
__global__ __launch_bounds__(512, 2) void k_gemm(const unsigned short* __restrict__ Ah,
                                                 const unsigned short* __restrict__ Bh,
                                                 const float* __restrict__ x2,
                                                 const float* __restrict__ y2,
                                                 float* __restrict__ partial) {
  __shared__ __align__(16) unsigned short sA[2][16384];   // [buf][h*8192 + r*64 + slot*8]
  __shared__ __align__(16) unsigned short sB[2][16384];
  __shared__ float rowacc[4][256];

  const int t    = threadIdx.x;
  const int w    = t >> 6;
  const int l    = t & 63;
  const int lrow = l & 15;
  const int lhi  = l >> 4;
  const int wm   = w >> 2, wn = w & 3;   // 2x4 wave grid
  const int bn   = blockIdx.x;           // 0..63 col-tiles (XCD = bn%8 -> L2-friendly)
  const int bm   = blockIdx.y;           // 0..15 row-tiles

  // staging source offset (pre-swizzled): row r=t>>3, slot s=t&7, kc=s^(r&7)
  const int sr  = t >> 3;
  const int skc = (t & 7) ^ (sr & 7);
  const size_t soff = (size_t)sr * D_DIM + (size_t)skc * 8;

  const unsigned short* Abase = Ah + (size_t)bm * 256 * D_DIM;
  const unsigned short* Bbase = Bh + (size_t)bn * 256 * D_DIM;

  auto stA = [&](int k1, int h) {
    const unsigned short* src = Abase + (size_t)h * 128 * D_DIM + k1 * 64 + soff;
    unsigned short* dst = &sA[k1 & 1][h * 8192 + w * 512];
    gll16(src, dst);
    gll16(src + 64 * D_DIM, dst + 4096);
  };
  auto stB = [&](int k1, int h) {
    const unsigned short* src = Bbase + (size_t)h * 128 * D_DIM + k1 * 64 + soff;
    unsigned short* dst = &sB[k1 & 1][h * 8192 + w * 512];
    gll16(src, dst);
    gll16(src + 64 * D_DIM, dst + 4096);
  };

  // ---- prologue: stage K-tile 0 (A+B), drain, publish ----
  stA(0, 0); stA(0, 1);
  stB(0, 0); stB(0, 1);
  asm volatile("s_waitcnt vmcnt(0)" ::: "memory");
  SBAR();

  // read-side swizzled slot offsets (lane-const): k-slice0 -> lhi, 1 -> lhi+4
  const int sl0 = ((lhi)     ^ (lrow & 7)) * 8;
  const int sl1 = ((lhi + 4) ^ (lrow & 7)) * 8;

  f16x8 afA[4], afB[4], bf0[4], bf1[4];
  {
    const unsigned short* Ab0 = &sA[0][wm * 8192 + lrow * 64];
    const unsigned short* Bb0 = &sB[0][(wn >> 1) * 8192 + ((wn & 1) * 64 + lrow) * 64];
#pragma unroll
    for (int nj = 0; nj < 4; ++nj)
      bf0[nj] = *(const f16x8*)(Bb0 + nj * 1024 + sl0);
#pragma unroll
    for (int mi = 0; mi < 4; ++mi)
      afA[mi] = *(const f16x8*)(Ab0 + mi * 1024 + sl0);
  }

  f32x4 acc[8][4];
#pragma unroll
  for (int mi = 0; mi < 8; ++mi)
#pragma unroll
    for (int nj = 0; nj < 4; ++nj)
      acc[mi][nj] = (f32x4){0.f, 0.f, 0.f, 0.f};

#pragma unroll
  for (int kt = 0; kt < 4; ++kt) {
    const unsigned short* Ab = &sA[kt & 1][wm * 8192 + lrow * 64];
    const unsigned short* Bb = &sB[kt & 1][(wn >> 1) * 8192 + ((wn & 1) * 64 + lrow) * 64];

    // ---- w0: MFMA(afA x bf0 -> acc0-3); read afB(sl0 hi-rows); stage kt+1 ----
    __builtin_amdgcn_s_setprio(1);
#pragma unroll
    for (int mi = 0; mi < 4; ++mi)
#pragma unroll
      for (int nj = 0; nj < 4; ++nj)
        acc[mi][nj] = __builtin_amdgcn_mfma_f32_16x16x32_f16(afA[mi], bf0[nj],
                                                             acc[mi][nj], 0, 0, 0);
    __builtin_amdgcn_s_setprio(0);
#pragma unroll
    for (int mi = 0; mi < 4; ++mi)
      afB[mi] = *(const f16x8*)(Ab + (64 + mi * 16) * 64 + sl0);
    if (kt < 3) { stA(kt + 1, 0); stA(kt + 1, 1); stB(kt + 1, 0); stB(kt + 1, 1); }
    SBAR();

    // ---- w1: MFMA(afB x bf0 -> acc4-7); read afA(sl1 lo-rows) + bf1(sl1) ----
    __builtin_amdgcn_s_setprio(1);
#pragma unroll
    for (int mi = 0; mi < 4; ++mi)
#pragma unroll
      for (int nj = 0; nj < 4; ++nj)
        acc[4 + mi][nj] = __builtin_amdgcn_mfma_f32_16x16x32_f16(afB[mi], bf0[nj],
                                                                 acc[4 + mi][nj], 0, 0, 0);
    __builtin_amdgcn_s_setprio(0);
#pragma unroll
    for (int mi = 0; mi < 4; ++mi)
      afA[mi] = *(const f16x8*)(Ab + mi * 1024 + sl1);
#pragma unroll
    for (int nj = 0; nj < 4; ++nj)
      bf1[nj] = *(const f16x8*)(Bb + nj * 1024 + sl1);
    SBAR();

    // ---- w2: MFMA(afA x bf1 -> acc0-3); read afB(sl1 hi-rows); vmcnt; publish ----
    __builtin_amdgcn_s_setprio(1);
#pragma unroll
    for (int mi = 0; mi < 4; ++mi)
#pragma unroll
      for (int nj = 0; nj < 4; ++nj)
        acc[mi][nj] = __builtin_amdgcn_mfma_f32_16x16x32_f16(afA[mi], bf1[nj],
                                                             acc[mi][nj], 0, 0, 0);
    __builtin_amdgcn_s_setprio(0);
#pragma unroll
    for (int mi = 0; mi < 4; ++mi)
      afB[mi] = *(const f16x8*)(Ab + (64 + mi * 16) * 64 + sl1);
    if (kt < 3) asm volatile("s_waitcnt vmcnt(0)" ::: "memory");
    SBAR();   // <- buf kt+1 published here (everyone's vmcnt cleared before)

    // ---- w3: MFMA(afB x bf1 -> acc4-7); read kt+1's first fragments ----
    __builtin_amdgcn_s_setprio(1);
#pragma unroll
    for (int mi = 0; mi < 4; ++mi)
#pragma unroll
      for (int nj = 0; nj < 4; ++nj)
        acc[4 + mi][nj] = __builtin_amdgcn_mfma_f32_16x16x32_f16(afB[mi], bf1[nj],
                                                                 acc[4 + mi][nj], 0, 0, 0);
    __builtin_amdgcn_s_setprio(0);
    if (kt < 3) {
      const unsigned short* Abn = &sA[(kt + 1) & 1][wm * 8192 + lrow * 64];
      const unsigned short* Bbn = &sB[(kt + 1) & 1][(wn >> 1) * 8192 + ((wn & 1) * 64 + lrow) * 64];
#pragma unroll
      for (int nj = 0; nj < 4; ++nj)
        bf0[nj] = *(const f16x8*)(Bbn + nj * 1024 + sl0);
#pragma unroll
      for (int mi = 0; mi < 4; ++mi)
        afA[mi] = *(const f16x8*)(Abn + mi * 1024 + sl0);
    }
    SBAR();
  }

  // ---- epilogue: dist + per-row partials over this block's 256 cols ----
  float yv[4];
#pragma unroll
  for (int nj = 0; nj < 4; ++nj)
    yv[nj] = y2[bn * 256 + wn * 64 + nj * 16 + lrow];

#pragma unroll
  for (int mi = 0; mi < 8; ++mi) {
    float4 x2v = *(const float4*)&x2[bm * 256 + wm * 128 + mi * 16 + lhi * 4];
    float xr[4] = {x2v.x, x2v.y, x2v.z, x2v.w};
    float rv[4];
#pragma unroll
    for (int rr = 0; rr < 4; ++rr) {
      float ssum = 0.f;
#pragma unroll
      for (int nj = 0; nj < 4; ++nj) {
        float d2 = xr[rr] + yv[nj] - 2.0f * acc[mi][nj][rr];
        d2 = fmaxf(d2, 0.0f);
        ssum += __builtin_amdgcn_sqrtf(d2 + EPSF);
      }
      ssum += __shfl_xor(ssum, 1, 64);
      ssum += __shfl_xor(ssum, 2, 64);
      ssum += __shfl_xor(ssum, 4, 64);
      ssum += __shfl_xor(ssum, 8, 64);
      rv[rr] = ssum;
    }
    if (lrow == 0)
      *(float4*)&rowacc[wn][wm * 128 + mi * 16 + lhi * 4] =
          make_float4(rv[0], rv[1], rv[2], rv[3]);
  }

  __syncthreads();
  if (t < 256)
    partial[(size_t)bn * N_IDE + bm * 256 + t] =
        rowacc[0][t] + rowacc[1][t] + rowacc[2][t] + rowacc[3][t];
}

// ---- Kernel 3: fused d-sum + loss (one launch instead of two + memset) ----
__global__ __launch_bounds__(256) void k_loss(const float* __restrict__ partial,
                                              float* __restrict__ out) {
  __shared__ float sd[N_IDE];
  __shared__ float wsum[4];
  int t = threadIdx.x;
  for (int k = t; k < N_IDE; k += 256) {
    float s = 0.f;
#pragma unroll
    for (int b = 0; b < 64; ++b) s += partial[(size_t)b * N_IDE + k];
    sd[k] = s;          // identical FP order in every block -> deterministic
  }
  __syncthreads();
  int tid = blockIdx.x * 256 + t;   // 65536 threads: 16 per i
  int i   = tid >> 4;
  int jl  = tid & 15;
  float di = sd[i];
  float s  = 0.f;
  for (int k = 0; k < 256; ++k) {
    float diff = (di - sd[jl + k * 16]) * INV_M;
    s += __builtin_amdgcn_sqrtf(diff * diff + EPSF);
  }
#pragma unroll
  for (int m = 1; m <= 32; m <<= 1) s += __shfl_xor(s, m, 64);
  if ((t & 63) == 0) wsum[t >> 6] = s;
  __syncthreads();
  if (t == 0) atomicAdd(out, wsum[0] + wsum[1] + wsum[2] + wsum[3]);
}

extern "C" void kernel_launch(void* const* d_in, const int* in_sizes, int n_in,
                              void* d_out, int out_size, void* d_ws, size_t ws_size,
                              hipStream_t stream) {
  (void)in_sizes; (void)n_in; (void)out_size; (void)ws_size;
  const float* ide = (const float*)d_in[0];
  const float* u   = (const float*)d_in[1];
  float* out = (float*)d_out;

  char* ws = (char*)d_ws;
  size_t off = 0;
  unsigned short* Ah = (unsigned short*)(ws + off); off += (size_t)N_IDE * D_DIM * 2;  // 2 MB
  unsigned short* Bh = (unsigned short*)(ws + off); off += (size_t)M_U  * D_DIM * 2;   // 8 MB
  float* x2      = (float*)(ws + off); off += (size_t)N_IDE * 4;
  float* y2      = (float*)(ws + off); off += (size_t)M_U * 4;
  float* partial = (float*)(ws + off); off += (size_t)64 * N_IDE * 4;                  // 1 MB

  k_conv<<<(N_IDE + M_U) / 4, 256, 0, stream>>>(ide, u, Ah, Bh, x2, y2, out);
  k_gemm<<<dim3(64, 16), 512, 0, stream>>>(Ah, Bh, x2, y2, partial);
  k_loss<<<256, 256, 0, stream>>>(partial, out);
}

// Round 5
// 150.624 us; speedup vs baseline: 1.6614x; 1.6614x over previous
//
#include <hip/hip_runtime.h>
#include <hip/hip_bf16.h>
#include <cstdint>

#define N_IDE 4096
#define M_U   16384
#define D_DIM 256
#define EPSF  1e-12f
#define INV_M (1.0f / 16384.0f)

typedef _Float16 f16x8 __attribute__((ext_vector_type(8)));
typedef float    f32x4 __attribute__((ext_vector_type(4)));

// ---- async global->LDS 16B copy. LDS dest = wave-uniform base + lane*16. ----
__device__ __forceinline__ void gll16(const void* g, void* l) {
  __builtin_amdgcn_global_load_lds(
      (const __attribute__((address_space(1))) void*)(uintptr_t)g,
      (__attribute__((address_space(3))) void*)(uint32_t)(uintptr_t)l,
      16, 0, 0);
}

__device__ __forceinline__ unsigned short f2h_bits(float f) {
  _Float16 h = (_Float16)f;
  return __builtin_bit_cast(unsigned short, h);
}

#define SBAR()  asm volatile("s_barrier" ::: "memory")

// ---- Kernel 1: fp32 -> f16 convert + row squared-norms (one wave per row) ----
__global__ __launch_bounds__(256) void k_conv(const float* __restrict__ ide,
                                              const float* __restrict__ u,
                                              unsigned short* __restrict__ Ah,
                                              unsigned short* __restrict__ Bh,
                                              float* __restrict__ x2,
                                              float* __restrict__ y2,
                                              float* __restrict__ out) {
  if (blockIdx.x == 0 && threadIdx.x == 0) out[0] = 0.f;   // replaces memset launch
  int gw = (blockIdx.x * 256 + threadIdx.x) >> 6;
  int l  = threadIdx.x & 63;
  const float4* src;
  ushort4* dst;
  float* nrm;
  if (gw < N_IDE) {
    src = (const float4*)(ide + (size_t)gw * D_DIM);
    dst = (ushort4*)(Ah + (size_t)gw * D_DIM);
    nrm = x2 + gw;
  } else {
    int r = gw - N_IDE;
    src = (const float4*)(u + (size_t)r * D_DIM);
    dst = (ushort4*)(Bh + (size_t)r * D_DIM);
    nrm = y2 + r;
  }
  float4 v = src[l];
  float s = v.x * v.x + v.y * v.y + v.z * v.z + v.w * v.w;
  ushort4 o;
  o.x = f2h_bits(v.x); o.y = f2h_bits(v.y);
  o.z = f2h_bits(v.z); o.w = f2h_bits(v.w);
  dst[l] = o;
#pragma unroll
  for (int m = 1; m <= 32; m <<= 1) s += __shfl_xor(s, m, 64);
  if (l == 0) *nrm = s;
}

// ---- Kernel 2: MFMA-first-window counted-vmcnt GEMM (BIT-IDENTICAL to r4) ----
// grid (64, 16), 512 threads = 8 waves (2M x 4N). Block tile 256x256, BK=64,
// K=256 -> 4 K-tiles, fully unrolled. Wave tile 128x64: acc[8][4] (128 AGPR).
// Each window runs the MFMA cluster FIRST (on fragments ds_read in the
// PREVIOUS window), then issues next window's ds_reads, then s_barrier ->
// a wave's reads drain while it sits at the barrier / other waves' MFMAs run.
__global__ __launch_bounds__(512, 2) void k_gemm(const unsigned short* __restrict__ Ah,
                                                 const unsigned short* __restrict__ Bh,
                                                 const float* __restrict__ x2,
                                                 const float* __restrict__ y2,
                                                 float* __restrict__ partial) {
  __shared__ __align__(16) unsigned short sA[2][16384];   // [buf][h*8192 + r*64 + slot*8]
  __shared__ __align__(16) unsigned short sB[2][16384];
  __shared__ float rowacc[4][256];

  const int t    = threadIdx.x;
  const int w    = t >> 6;
  const int l    = t & 63;
  const int lrow = l & 15;
  const int lhi  = l >> 4;
  const int wm   = w >> 2, wn = w & 3;   // 2x4 wave grid
  const int bn   = blockIdx.x;           // 0..63 col-tiles
  const int bm   = blockIdx.y;           // 0..15 row-tiles

  // staging source offset (pre-swizzled): row r=t>>3, slot s=t&7, kc=s^(r&7)
  const int sr  = t >> 3;
  const int skc = (t & 7) ^ (sr & 7);
  const size_t soff = (size_t)sr * D_DIM + (size_t)skc * 8;

  const unsigned short* Abase = Ah + (size_t)bm * 256 * D_DIM;
  const unsigned short* Bbase = Bh + (size_t)bn * 256 * D_DIM;

  auto stA = [&](int k1, int h) {
    const unsigned short* src = Abase + (size_t)h * 128 * D_DIM + k1 * 64 + soff;
    unsigned short* dst = &sA[k1 & 1][h * 8192 + w * 512];
    gll16(src, dst);
    gll16(src + 64 * D_DIM, dst + 4096);
  };
  auto stB = [&](int k1, int h) {
    const unsigned short* src = Bbase + (size_t)h * 128 * D_DIM + k1 * 64 + soff;
    unsigned short* dst = &sB[k1 & 1][h * 8192 + w * 512];
    gll16(src, dst);
    gll16(src + 64 * D_DIM, dst + 4096);
  };

  // ---- prologue: stage K-tile 0 (A+B), drain, publish ----
  stA(0, 0); stA(0, 1);
  stB(0, 0); stB(0, 1);
  asm volatile("s_waitcnt vmcnt(0)" ::: "memory");
  SBAR();

  // read-side swizzled slot offsets (lane-const): k-slice0 -> lhi, 1 -> lhi+4
  const int sl0 = ((lhi)     ^ (lrow & 7)) * 8;
  const int sl1 = ((lhi + 4) ^ (lrow & 7)) * 8;

  f16x8 afA[4], afB[4], bf0[4], bf1[4];
  {
    const unsigned short* Ab0 = &sA[0][wm * 8192 + lrow * 64];
    const unsigned short* Bb0 = &sB[0][(wn >> 1) * 8192 + ((wn & 1) * 64 + lrow) * 64];
#pragma unroll
    for (int nj = 0; nj < 4; ++nj)
      bf0[nj] = *(const f16x8*)(Bb0 + nj * 1024 + sl0);
#pragma unroll
    for (int mi = 0; mi < 4; ++mi)
      afA[mi] = *(const f16x8*)(Ab0 + mi * 1024 + sl0);
  }

  f32x4 acc[8][4];
#pragma unroll
  for (int mi = 0; mi < 8; ++mi)
#pragma unroll
    for (int nj = 0; nj < 4; ++nj)
      acc[mi][nj] = (f32x4){0.f, 0.f, 0.f, 0.f};

#pragma unroll
  for (int kt = 0; kt < 4; ++kt) {
    const unsigned short* Ab = &sA[kt & 1][wm * 8192 + lrow * 64];
    const unsigned short* Bb = &sB[kt & 1][(wn >> 1) * 8192 + ((wn & 1) * 64 + lrow) * 64];

    // ---- w0: MFMA(afA x bf0 -> acc0-3); read afB(sl0 hi-rows); stage kt+1 ----
    __builtin_amdgcn_s_setprio(1);
#pragma unroll
    for (int mi = 0; mi < 4; ++mi)
#pragma unroll
      for (int nj = 0; nj < 4; ++nj)
        acc[mi][nj] = __builtin_amdgcn_mfma_f32_16x16x32_f16(afA[mi], bf0[nj],
                                                             acc[mi][nj], 0, 0, 0);
    __builtin_amdgcn_s_setprio(0);
#pragma unroll
    for (int mi = 0; mi < 4; ++mi)
      afB[mi] = *(const f16x8*)(Ab + (64 + mi * 16) * 64 + sl0);
    if (kt < 3) { stA(kt + 1, 0); stA(kt + 1, 1); stB(kt + 1, 0); stB(kt + 1, 1); }
    SBAR();

    // ---- w1: MFMA(afB x bf0 -> acc4-7); read afA(sl1 lo-rows) + bf1(sl1) ----
    __builtin_amdgcn_s_setprio(1);
#pragma unroll
    for (int mi = 0; mi < 4; ++mi)
#pragma unroll
      for (int nj = 0; nj < 4; ++nj)
        acc[4 + mi][nj] = __builtin_amdgcn_mfma_f32_16x16x32_f16(afB[mi], bf0[nj],
                                                                 acc[4 + mi][nj], 0, 0, 0);
    __builtin_amdgcn_s_setprio(0);
#pragma unroll
    for (int mi = 0; mi < 4; ++mi)
      afA[mi] = *(const f16x8*)(Ab + mi * 1024 + sl1);
#pragma unroll
    for (int nj = 0; nj < 4; ++nj)
      bf1[nj] = *(const f16x8*)(Bb + nj * 1024 + sl1);
    SBAR();

    // ---- w2: MFMA(afA x bf1 -> acc0-3); read afB(sl1 hi-rows); vmcnt; publish ----
    __builtin_amdgcn_s_setprio(1);
#pragma unroll
    for (int mi = 0; mi < 4; ++mi)
#pragma unroll
      for (int nj = 0; nj < 4; ++nj)
        acc[mi][nj] = __builtin_amdgcn_mfma_f32_16x16x32_f16(afA[mi], bf1[nj],
                                                             acc[mi][nj], 0, 0, 0);
    __builtin_amdgcn_s_setprio(0);
#pragma unroll
    for (int mi = 0; mi < 4; ++mi)
      afB[mi] = *(const f16x8*)(Ab + (64 + mi * 16) * 64 + sl1);
    if (kt < 3) asm volatile("s_waitcnt vmcnt(0)" ::: "memory");
    SBAR();   // <- buf kt+1 published here (everyone's vmcnt cleared before)

    // ---- w3: MFMA(afB x bf1 -> acc4-7); read kt+1's first fragments ----
    __builtin_amdgcn_s_setprio(1);
#pragma unroll
    for (int mi = 0; mi < 4; ++mi)
#pragma unroll
      for (int nj = 0; nj < 4; ++nj)
        acc[4 + mi][nj] = __builtin_amdgcn_mfma_f32_16x16x32_f16(afB[mi], bf1[nj],
                                                                 acc[4 + mi][nj], 0, 0, 0);
    __builtin_amdgcn_s_setprio(0);
    if (kt < 3) {
      const unsigned short* Abn = &sA[(kt + 1) & 1][wm * 8192 + lrow * 64];
      const unsigned short* Bbn = &sB[(kt + 1) & 1][(wn >> 1) * 8192 + ((wn & 1) * 64 + lrow) * 64];
#pragma unroll
      for (int nj = 0; nj < 4; ++nj)
        bf0[nj] = *(const f16x8*)(Bbn + nj * 1024 + sl0);
#pragma unroll
      for (int mi = 0; mi < 4; ++mi)
        afA[mi] = *(const f16x8*)(Abn + mi * 1024 + sl0);
    }
    SBAR();
  }

  // ---- epilogue: dist + per-row partials over this block's 256 cols ----
  float yv[4];
#pragma unroll
  for (int nj = 0; nj < 4; ++nj)
    yv[nj] = y2[bn * 256 + wn * 64 + nj * 16 + lrow];

#pragma unroll
  for (int mi = 0; mi < 8; ++mi) {
    float4 x2v = *(const float4*)&x2[bm * 256 + wm * 128 + mi * 16 + lhi * 4];
    float xr[4] = {x2v.x, x2v.y, x2v.z, x2v.w};
    float rv[4];
#pragma unroll
    for (int rr = 0; rr < 4; ++rr) {
      float ssum = 0.f;
#pragma unroll
      for (int nj = 0; nj < 4; ++nj) {
        float d2 = xr[rr] + yv[nj] - 2.0f * acc[mi][nj][rr];
        d2 = fmaxf(d2, 0.0f);
        ssum += __builtin_amdgcn_sqrtf(d2 + EPSF);
      }
      ssum += __shfl_xor(ssum, 1, 64);
      ssum += __shfl_xor(ssum, 2, 64);
      ssum += __shfl_xor(ssum, 4, 64);
      ssum += __shfl_xor(ssum, 8, 64);
      rv[rr] = ssum;
    }
    if (lrow == 0)
      *(float4*)&rowacc[wn][wm * 128 + mi * 16 + lhi * 4] =
          make_float4(rv[0], rv[1], rv[2], rv[3]);
  }

  __syncthreads();
  if (t < 256)
    partial[(size_t)bn * N_IDE + bm * 256 + t] =
        rowacc[0][t] + rowacc[1][t] + rowacc[2][t] + rowacc[3][t];
}

// ---- Kernel 3: d[k] = sum over 64 bn-slices (16 blocks, ~1 MB L2 reads) ----
__global__ __launch_bounds__(256) void k_dsum(const float* __restrict__ partial,
                                              float* __restrict__ d) {
  int k = blockIdx.x * 256 + threadIdx.x;
  float s = 0.f;
#pragma unroll
  for (int b = 0; b < 64; ++b) s += partial[(size_t)b * N_IDE + k];
  d[k] = s;
}

// ---- Kernel 4: loss = sum_{i,j} sqrt(((d_i-d_j)*INV_M)^2 + eps) ----
__global__ __launch_bounds__(256) void k_loss(const float* __restrict__ d,
                                              float* __restrict__ out) {
  __shared__ float sd[N_IDE];
  __shared__ float wsum[4];
  int t = threadIdx.x;
  for (int k = t; k < N_IDE; k += 256) sd[k] = d[k];
  __syncthreads();
  int tid = blockIdx.x * 256 + t;   // 65536 threads: 16 per i
  int i   = tid >> 4;
  int jl  = tid & 15;
  float di = sd[i];
  float s  = 0.f;
  for (int k = 0; k < 256; ++k) {
    float diff = (di - sd[jl + k * 16]) * INV_M;
    s += __builtin_amdgcn_sqrtf(diff * diff + EPSF);
  }
#pragma unroll
  for (int m = 1; m <= 32; m <<= 1) s += __shfl_xor(s, m, 64);
  if ((t & 63) == 0) wsum[t >> 6] = s;
  __syncthreads();
  if (t == 0) atomicAdd(out, wsum[0] + wsum[1] + wsum[2] + wsum[3]);
}

extern "C" void kernel_launch(void* const* d_in, const int* in_sizes, int n_in,
                              void* d_out, int out_size, void* d_ws, size_t ws_size,
                              hipStream_t stream) {
  (void)in_sizes; (void)n_in; (void)out_size; (void)ws_size;
  const float* ide = (const float*)d_in[0];
  const float* u   = (const float*)d_in[1];
  float* out = (float*)d_out;

  char* ws = (char*)d_ws;
  size_t off = 0;
  unsigned short* Ah = (unsigned short*)(ws + off); off += (size_t)N_IDE * D_DIM * 2;  // 2 MB
  unsigned short* Bh = (unsigned short*)(ws + off); off += (size_t)M_U  * D_DIM * 2;   // 8 MB
  float* x2      = (float*)(ws + off); off += (size_t)N_IDE * 4;
  float* y2      = (float*)(ws + off); off += (size_t)M_U * 4;
  float* partial = (float*)(ws + off); off += (size_t)64 * N_IDE * 4;                  // 1 MB
  float* dvec    = (float*)(ws + off); off += (size_t)N_IDE * 4;

  k_conv<<<(N_IDE + M_U) / 4, 256, 0, stream>>>(ide, u, Ah, Bh, x2, y2, out);
  k_gemm<<<dim3(64, 16), 512, 0, stream>>>(Ah, Bh, x2, y2, partial);
  k_dsum<<<N_IDE / 256, 256, 0, stream>>>(partial, dvec);
  k_loss<<<256, 256, 0, stream>>>(dvec, out);
}